// Round 11
// baseline (5802.983 us; speedup 1.0000x reference)
//
#include <hip/hip_runtime.h>

#define SEQ_LEN 256
#define SPIKE_STEPS 7
#define T_TOTAL (SEQ_LEN * SPIKE_STEPS)
#define BATCH 128
#define IN_DIM 96
#define HIDDEN 512
#define OUT_DIM 2

#define WROWS (HIDDEN + 1)   // +1 zero row for act-list padding
#define GW 16                // tier-2 pipeline group width (2-deep, 32 outstanding)
#define REG_J 128            // rows [0,128) cached in per-thread VGPRs

// d_ws layout: W0T [96*512] | W1T [513*512] | W2T [513*512] | ctr[128] | zbuf[B][T][8] u64
#define W0T_OFF 0
#define W1T_OFF (IN_DIM * HIDDEN)
#define W2T_OFF (W1T_OFF + WROWS * HIDDEN)
#define CTR_BYTE_OFF ((size_t)(W2T_OFF + WROWS * HIDDEN) * sizeof(float))
#define ZBUF_BYTE_OFF (CTR_BYTE_OFF + 1024)

__global__ void transpose_kernel(const float* __restrict__ in, float* __restrict__ out,
                                 int rows, int cols) {
    int idx = blockIdx.x * blockDim.x + threadIdx.x;
    if (idx < rows * cols) {
        int r = idx / cols, c = idx - r * cols;
        out[c * rows + r] = in[idx];
    }
}

// Hybrid row-sum: tier-1 = register-resident rows j<128 via wave-uniform
// masked adds (mask words in SGPRs -> s_cbranch around each add; only taken
// adds cost VALU). Tier-2 = r7's depth-2 16-wide pipelined L2 loads over the
// compacted act list (rows >= 128, zero-row padded). Group-0 loads are issued
// BEFORE tier-1 so VMEM latency hides the scalar adds. Accumulation order per
// h: ascending j in [0,128) then ascending act + zeros => bit-identical to
// the plain in-order sum.
#define TIER1(MW, BASE) \
    { _Pragma("unroll") for (int j = 0; j < 32; ++j) \
        if ((MW) & (1u << j)) cur = __fadd_rn(cur, wr[(BASE) + j]); }

__device__ __forceinline__ float row_sum_hybrid(const float* __restrict__ W,
                                                const int* __restrict__ act,
                                                int npad, int tid,
                                                unsigned mw0, unsigned mw1,
                                                unsigned mw2, unsigned mw3,
                                                const float (&wr)[REG_J]) {
    float buf[GW];
    if (npad > 0) {
        #pragma unroll
        for (int k = 0; k < GW; ++k) buf[k] = W[act[k] * HIDDEN + tid];
    }

    float cur = 0.f;
    TIER1(mw0, 0); TIER1(mw1, 32); TIER1(mw2, 64); TIER1(mw3, 96);

    if (npad > 0) {
        for (int n = GW; n < npad; n += GW) {
            float nxt[GW];
            #pragma unroll
            for (int k = 0; k < GW; ++k) nxt[k] = W[act[n + k] * HIDDEN + tid];
            #pragma unroll
            for (int k = 0; k < GW; ++k) cur = __fadd_rn(cur, buf[k]);
            #pragma unroll
            for (int k = 0; k < GW; ++k) buf[k] = nxt[k];
        }
        #pragma unroll
        for (int k = 0; k < GW; ++k) cur = __fadd_rn(cur, buf[k]);
    }
    return cur;
}

// Two-stage pipeline: even blocks = producer (layer0+layer1), odd = consumer
// (layer2+output); per-step mask handoff through L2 (relaxed agent atomics).
// amdgpu_waves_per_eu(2,2) pins the register budget at 256/wave so the
// 128-float wr[] stays in VGPRs (r5 spilled because the allocator targeted
// 4 waves/SIMD; block=512 runs 2 waves/EU regardless, so this costs nothing).
__attribute__((amdgpu_flat_work_group_size(512, 512), amdgpu_waves_per_eu(2, 2)))
__global__ void snn_pipe_kernel(const float* __restrict__ x,     // [256,128,96]
                                const float* __restrict__ Wout,  // [2,512]
                                const float* __restrict__ betas, // [3]
                                const float* __restrict__ thrs,  // [3]
                                const float* __restrict__ W0T,   // [96,512]
                                const float* __restrict__ W1T,   // [513,512]
                                const float* __restrict__ W2T,   // [513,512]
                                unsigned long long* __restrict__ zbuf,
                                int* __restrict__ ctr,
                                float* __restrict__ out)         // [256,128,2]
{
    const int b    = blockIdx.x >> 1;
    const int role = blockIdx.x & 1;
    const int tid  = threadIdx.x;
    const int lane = tid & 63;
    const int wid  = tid >> 6;

    __shared__ float xs[IN_DIM];
    __shared__ unsigned long long zmf[8];   // full 512-bit spike mask
    __shared__ unsigned long long zmc[8];   // filtered (j>=REG_J) mask
    __shared__ int act[HIDDEN + GW];
    __shared__ float red[16];

    if (role == 0) {
        // ---------------- producer: layer0 + layer1 ----------------
        const float beta0 = betas[0], beta1 = betas[1];
        const float thr0  = thrs[0],  thr1  = thrs[1];
        float mem0 = 0.f, mem1 = 0.f;
        unsigned long long* zb = zbuf + (size_t)b * T_TOTAL * 8;

        float wr[REG_J];
        #pragma unroll
        for (int j = 0; j < REG_J; ++j) wr[j] = W1T[j * HIDDEN + tid];

        for (int i = 0; i < SEQ_LEN; ++i) {
            if (tid < IN_DIM) xs[tid] = x[(i * BATCH + b) * IN_DIM + tid];
            __syncthreads();

            float cur0 = 0.f;
            #pragma unroll 8
            for (int k = 0; k < IN_DIM; ++k)
                cur0 = __fmaf_rn(xs[k], W0T[k * HIDDEN + tid], cur0);

            for (int s = 0; s < SPIKE_STEPS; ++s) {
                const int t = i * SPIKE_STEPS + s;

                // layer 0 LIF
                bool reset0 = (mem0 - thr0) > 0.f;
                mem0 = reset0 ? 0.f : __fadd_rn(__fmul_rn(beta0, mem0), cur0);
                bool z0 = (mem0 - thr0) > 0.f;
                unsigned long long balf = __ballot(z0);
                unsigned long long balc = __ballot(z0 && (tid >= REG_J));
                if (lane == 0) { zmf[wid] = balf; zmc[wid] = balc; }
                __syncthreads();

                unsigned mw0, mw1, mw2, mw3;
                {
                    unsigned long long w0 = zmf[0], w1 = zmf[1];
                    mw0 = __builtin_amdgcn_readfirstlane((unsigned)w0);
                    mw1 = __builtin_amdgcn_readfirstlane((unsigned)(w0 >> 32));
                    mw2 = __builtin_amdgcn_readfirstlane((unsigned)w1);
                    mw3 = __builtin_amdgcn_readfirstlane((unsigned)(w1 >> 32));
                }

                int nact, npad;
                {
                    int pre = 0, total = 0;
                    #pragma unroll
                    for (int q = 0; q < 8; ++q) {
                        int p = __popcll(zmc[q]);
                        total += p;
                        if (q < wid) pre += p;
                    }
                    int rank = pre + __popcll(zmc[wid] & ((1ull << lane) - 1ull));
                    if (z0 && (tid >= REG_J)) act[rank] = tid;
                    nact = total;
                    npad = (nact + GW - 1) & ~(GW - 1);
                    if (tid < npad - nact) act[nact + tid] = HIDDEN;  // zero-row pads
                }
                __syncthreads();

                float cur1 = row_sum_hybrid(W1T, act, npad, tid, mw0, mw1, mw2, mw3, wr);

                // layer 1 LIF
                bool reset1 = (mem1 - thr1) > 0.f;
                mem1 = reset1 ? 0.f : __fadd_rn(__fmul_rn(beta1, mem1), cur1);
                bool z1 = (mem1 - thr1) > 0.f;

                unsigned long long bal1 = __ballot(z1);
                if (lane == 0)
                    __hip_atomic_store(&zb[(size_t)t * 8 + wid], bal1,
                                       __ATOMIC_RELAXED, __HIP_MEMORY_SCOPE_AGENT);
                __syncthreads();   // vmcnt(0) drain before barrier => masks visible
                if (tid == 0)
                    __hip_atomic_store(&ctr[b], t + 1,
                                       __ATOMIC_RELAXED, __HIP_MEMORY_SCOPE_AGENT);
            }
        }
    } else {
        // ---------------- consumer: layer2 + output ----------------
        const float beta2 = betas[2];
        const float thr2  = thrs[2];
        const float wo0 = Wout[tid];
        const float wo1 = Wout[HIDDEN + tid];
        float mem2 = 0.f, mo0 = 0.f, mo1 = 0.f;
        const unsigned long long* zb = zbuf + (size_t)b * T_TOTAL * 8;

        float wr[REG_J];
        #pragma unroll
        for (int j = 0; j < REG_J; ++j) wr[j] = W2T[j * HIDDEN + tid];

        for (int i = 0; i < SEQ_LEN; ++i) {
            float so0 = 0.f, so1 = 0.f;

            for (int s = 0; s < SPIKE_STEPS; ++s) {
                const int t = i * SPIKE_STEPS + s;

                if (tid == 0) {
                    while (__hip_atomic_load(&ctr[b], __ATOMIC_RELAXED,
                                             __HIP_MEMORY_SCOPE_AGENT) < t + 1)
                        __builtin_amdgcn_s_sleep(1);
                }
                __syncthreads();

                if (tid < 8)
                    zmf[tid] = __hip_atomic_load(&zb[(size_t)t * 8 + tid],
                                                 __ATOMIC_RELAXED, __HIP_MEMORY_SCOPE_AGENT);
                __syncthreads();

                bool z1 = (zmf[wid] >> lane) & 1ull;
                {
                    unsigned long long balc = __ballot(z1 && (tid >= REG_J));
                    if (lane == 0) zmc[wid] = balc;
                }
                __syncthreads();

                unsigned mw0, mw1, mw2, mw3;
                {
                    unsigned long long w0 = zmf[0], w1 = zmf[1];
                    mw0 = __builtin_amdgcn_readfirstlane((unsigned)w0);
                    mw1 = __builtin_amdgcn_readfirstlane((unsigned)(w0 >> 32));
                    mw2 = __builtin_amdgcn_readfirstlane((unsigned)w1);
                    mw3 = __builtin_amdgcn_readfirstlane((unsigned)(w1 >> 32));
                }

                int nact, npad;
                {
                    int pre = 0, total = 0;
                    #pragma unroll
                    for (int q = 0; q < 8; ++q) {
                        int p = __popcll(zmc[q]);
                        total += p;
                        if (q < wid) pre += p;
                    }
                    int rank = pre + __popcll(zmc[wid] & ((1ull << lane) - 1ull));
                    if (z1 && (tid >= REG_J)) act[rank] = tid;
                    nact = total;
                    npad = (nact + GW - 1) & ~(GW - 1);
                    if (tid < npad - nact) act[nact + tid] = HIDDEN;  // zero-row pads
                }
                __syncthreads();

                float cur2 = row_sum_hybrid(W2T, act, npad, tid, mw0, mw1, mw2, mw3, wr);

                // layer 2 LIF
                bool reset2 = (mem2 - thr2) > 0.f;
                mem2 = reset2 ? 0.f : __fadd_rn(__fmul_rn(beta2, mem2), cur2);
                bool z2 = (mem2 - thr2) > 0.f;

                // output integrator
                float c0 = z2 ? wo0 : 0.f;
                float c1 = z2 ? wo1 : 0.f;
                #pragma unroll
                for (int off = 32; off > 0; off >>= 1) {
                    c0 += __shfl_down(c0, off);
                    c1 += __shfl_down(c1, off);
                }
                if (lane == 0) { red[wid * 2] = c0; red[wid * 2 + 1] = c1; }
                __syncthreads();
                if (tid == 0) {
                    float r0 = 0.f, r1 = 0.f;
                    #pragma unroll
                    for (int q = 0; q < 8; ++q) { r0 += red[q * 2]; r1 += red[q * 2 + 1]; }
                    mo0 += r0; mo1 += r1;
                    so0 += mo0; so1 += mo1;
                }
            }

            if (tid == 0) {
                out[(i * BATCH + b) * OUT_DIM + 0] = so0 / 7.0f;
                out[(i * BATCH + b) * OUT_DIM + 1] = so1 / 7.0f;
            }
        }
    }
}

extern "C" void kernel_launch(void* const* d_in, const int* in_sizes, int n_in,
                              void* d_out, int out_size, void* d_ws, size_t ws_size,
                              hipStream_t stream) {
    const float* x     = (const float*)d_in[0];
    const float* W0    = (const float*)d_in[1];
    const float* W1    = (const float*)d_in[2];
    const float* W2    = (const float*)d_in[3];
    const float* Wout  = (const float*)d_in[4];
    const float* betas = (const float*)d_in[5];
    const float* thrs  = (const float*)d_in[6];
    float* out = (float*)d_out;

    float* ws  = (float*)d_ws;
    float* W0T = ws + W0T_OFF;
    float* W1T = ws + W1T_OFF;
    float* W2T = ws + W2T_OFF;
    int* ctr = (int*)((char*)d_ws + CTR_BYTE_OFF);
    unsigned long long* zbuf = (unsigned long long*)((char*)d_ws + ZBUF_BYTE_OFF);

    {
        int n = HIDDEN * IN_DIM;
        transpose_kernel<<<(n + 255) / 256, 256, 0, stream>>>(W0, W0T, HIDDEN, IN_DIM);
    }
    {
        int n = HIDDEN * HIDDEN;
        transpose_kernel<<<(n + 255) / 256, 256, 0, stream>>>(W1, W1T, HIDDEN, HIDDEN);
        transpose_kernel<<<(n + 255) / 256, 256, 0, stream>>>(W2, W2T, HIDDEN, HIDDEN);
    }

    // zero the pad row (index 512) of W1T/W2T, and the progress counters
    hipMemsetAsync(W1T + (size_t)HIDDEN * HIDDEN, 0, HIDDEN * sizeof(float), stream);
    hipMemsetAsync(W2T + (size_t)HIDDEN * HIDDEN, 0, HIDDEN * sizeof(float), stream);
    hipMemsetAsync((char*)d_ws + CTR_BYTE_OFF, 0, 1024, stream);

    snn_pipe_kernel<<<2 * BATCH, HIDDEN, 0, stream>>>(
        x, Wout, betas, thrs, W0T, W1T, W2T, zbuf, ctr, out);
}

// Round 12
// 4299.501 us; speedup vs baseline: 1.3497x; 1.3497x over previous
//
#include <hip/hip_runtime.h>

#define SEQ_LEN 256
#define SPIKE_STEPS 7
#define T_TOTAL (SEQ_LEN * SPIKE_STEPS)
#define BATCH 128
#define IN_DIM 96
#define HIDDEN 512
#define OUT_DIM 2

// Weight buffers carry an extra all-zero row (index 512) used to pad the
// active list to a multiple of 16 — enables a fixed-trip-count, software-
// pipelined inner loop with two 16-load groups in flight.
#define WROWS (HIDDEN + 1)
#define GW 16   // pipeline group width (2-deep => 32 outstanding loads < vmcnt cap)

// d_ws layout: W0T [96*512] | W1T [513*512] | W2T [513*512] | ctr[128] | zbuf[B][T][8] u64
#define W0T_OFF 0
#define W1T_OFF (IN_DIM * HIDDEN)
#define W2T_OFF (W1T_OFF + WROWS * HIDDEN)
#define CTR_BYTE_OFF ((size_t)(W2T_OFF + WROWS * HIDDEN) * sizeof(float))
#define ZBUF_BYTE_OFF (CTR_BYTE_OFF + 1024)

__global__ void transpose_kernel(const float* __restrict__ in, float* __restrict__ out,
                                 int rows, int cols) {
    int idx = blockIdx.x * blockDim.x + threadIdx.x;
    if (idx < rows * cols) {
        int r = idx / cols, c = idx - r * cols;
        out[c * rows + r] = in[idx];
    }
}

// Sum of active weight rows, software-pipelined: 16-row groups, next group's
// loads issued before current group's adds => compiler emits vmcnt(16) not
// vmcnt(0); ~32 outstanding loads per thread. npad multiple of 16 via zero-row
// padding => no remainder loop. Add order = ascending act + trailing zeros =>
// bit-identical to the simple in-order sum.
__device__ __forceinline__ float row_sum_pipelined(const float* __restrict__ W,
                                                   const int* __restrict__ act,
                                                   int npad, int tid) {
    float cur = 0.f;
    if (npad > 0) {
        float buf[GW];
        #pragma unroll
        for (int k = 0; k < GW; ++k) buf[k] = W[act[k] * HIDDEN + tid];
        for (int n = GW; n < npad; n += GW) {
            float nxt[GW];
            #pragma unroll
            for (int k = 0; k < GW; ++k) nxt[k] = W[act[n + k] * HIDDEN + tid];
            #pragma unroll
            for (int k = 0; k < GW; ++k) cur = __fadd_rn(cur, buf[k]);
            #pragma unroll
            for (int k = 0; k < GW; ++k) buf[k] = nxt[k];
        }
        #pragma unroll
        for (int k = 0; k < GW; ++k) cur = __fadd_rn(cur, buf[k]);
    }
    return cur;
}

// Round-2 two-stage pipeline: even blocks = producer (layer0+layer1),
// odd = consumer (layer2+output); per-step mask handoff through L2 with
// relaxed agent-scope atomics.
__launch_bounds__(512, 1)
__global__ void snn_pipe_kernel(const float* __restrict__ x,     // [256,128,96]
                                const float* __restrict__ Wout,  // [2,512]
                                const float* __restrict__ betas, // [3]
                                const float* __restrict__ thrs,  // [3]
                                const float* __restrict__ W0T,   // [96,512]
                                const float* __restrict__ W1T,   // [513,512]
                                const float* __restrict__ W2T,   // [513,512]
                                unsigned long long* __restrict__ zbuf,
                                int* __restrict__ ctr,
                                float* __restrict__ out)         // [256,128,2]
{
    const int b    = blockIdx.x >> 1;
    const int role = blockIdx.x & 1;
    const int tid  = threadIdx.x;
    const int lane = tid & 63;
    const int wid  = tid >> 6;

    __shared__ float xs[IN_DIM];
    __shared__ unsigned long long zm[8];
    __shared__ int act[HIDDEN + GW];
    __shared__ float red[16];

    if (role == 0) {
        // ---------------- producer: layer0 + layer1 ----------------
        const float beta0 = betas[0], beta1 = betas[1];
        const float thr0  = thrs[0],  thr1  = thrs[1];
        float mem0 = 0.f, mem1 = 0.f;
        unsigned long long* zb = zbuf + (size_t)b * T_TOTAL * 8;

        for (int i = 0; i < SEQ_LEN; ++i) {
            if (tid < IN_DIM) xs[tid] = x[(i * BATCH + b) * IN_DIM + tid];
            __syncthreads();

            float cur0 = 0.f;
            #pragma unroll 8
            for (int k = 0; k < IN_DIM; ++k)
                cur0 = __fmaf_rn(xs[k], W0T[k * HIDDEN + tid], cur0);

            for (int s = 0; s < SPIKE_STEPS; ++s) {
                const int t = i * SPIKE_STEPS + s;

                // layer 0 LIF
                bool reset0 = (mem0 - thr0) > 0.f;
                mem0 = reset0 ? 0.f : __fadd_rn(__fmul_rn(beta0, mem0), cur0);
                bool z0 = (mem0 - thr0) > 0.f;
                unsigned long long bal = __ballot(z0);
                if (lane == 0) zm[wid] = bal;
                __syncthreads();

                int nact, npad;
                {
                    int pre = 0, total = 0;
                    #pragma unroll
                    for (int q = 0; q < 8; ++q) {
                        int p = __popcll(zm[q]);
                        total += p;
                        if (q < wid) pre += p;
                    }
                    int rank = pre + __popcll(zm[wid] & ((1ull << lane) - 1ull));
                    if (z0) act[rank] = tid;
                    nact = total;
                    npad = (nact + GW - 1) & ~(GW - 1);
                    if (tid < npad - nact) act[nact + tid] = HIDDEN;  // zero-row pads
                }
                __syncthreads();

                float cur1 = row_sum_pipelined(W1T, act, npad, tid);

                // layer 1 LIF
                bool reset1 = (mem1 - thr1) > 0.f;
                mem1 = reset1 ? 0.f : __fadd_rn(__fmul_rn(beta1, mem1), cur1);
                bool z1 = (mem1 - thr1) > 0.f;

                unsigned long long bal1 = __ballot(z1);
                if (lane == 0)
                    __hip_atomic_store(&zb[(size_t)t * 8 + wid], bal1,
                                       __ATOMIC_RELAXED, __HIP_MEMORY_SCOPE_AGENT);
                __syncthreads();   // vmcnt(0) drain before barrier => masks visible
                if (tid == 0)
                    __hip_atomic_store(&ctr[b], t + 1,
                                       __ATOMIC_RELAXED, __HIP_MEMORY_SCOPE_AGENT);
            }
        }
    } else {
        // ---------------- consumer: layer2 + output ----------------
        const float beta2 = betas[2];
        const float thr2  = thrs[2];
        const float wo0 = Wout[tid];
        const float wo1 = Wout[HIDDEN + tid];
        float mem2 = 0.f, mo0 = 0.f, mo1 = 0.f;
        const unsigned long long* zb = zbuf + (size_t)b * T_TOTAL * 8;

        for (int i = 0; i < SEQ_LEN; ++i) {
            float so0 = 0.f, so1 = 0.f;

            for (int s = 0; s < SPIKE_STEPS; ++s) {
                const int t = i * SPIKE_STEPS + s;

                if (tid == 0) {
                    while (__hip_atomic_load(&ctr[b], __ATOMIC_RELAXED,
                                             __HIP_MEMORY_SCOPE_AGENT) < t + 1)
                        __builtin_amdgcn_s_sleep(1);
                }
                __syncthreads();

                if (tid < 8)
                    zm[tid] = __hip_atomic_load(&zb[(size_t)t * 8 + tid],
                                                __ATOMIC_RELAXED, __HIP_MEMORY_SCOPE_AGENT);
                __syncthreads();

                bool z1 = (zm[wid] >> lane) & 1ull;
                int nact, npad;
                {
                    int pre = 0, total = 0;
                    #pragma unroll
                    for (int q = 0; q < 8; ++q) {
                        int p = __popcll(zm[q]);
                        total += p;
                        if (q < wid) pre += p;
                    }
                    int rank = pre + __popcll(zm[wid] & ((1ull << lane) - 1ull));
                    if (z1) act[rank] = tid;
                    nact = total;
                    npad = (nact + GW - 1) & ~(GW - 1);
                    if (tid < npad - nact) act[nact + tid] = HIDDEN;  // zero-row pads
                }
                __syncthreads();

                float cur2 = row_sum_pipelined(W2T, act, npad, tid);

                // layer 2 LIF
                bool reset2 = (mem2 - thr2) > 0.f;
                mem2 = reset2 ? 0.f : __fadd_rn(__fmul_rn(beta2, mem2), cur2);
                bool z2 = (mem2 - thr2) > 0.f;

                // output integrator
                float c0 = z2 ? wo0 : 0.f;
                float c1 = z2 ? wo1 : 0.f;
                #pragma unroll
                for (int off = 32; off > 0; off >>= 1) {
                    c0 += __shfl_down(c0, off);
                    c1 += __shfl_down(c1, off);
                }
                if (lane == 0) { red[wid * 2] = c0; red[wid * 2 + 1] = c1; }
                __syncthreads();
                if (tid == 0) {
                    float r0 = 0.f, r1 = 0.f;
                    #pragma unroll
                    for (int q = 0; q < 8; ++q) { r0 += red[q * 2]; r1 += red[q * 2 + 1]; }
                    mo0 += r0; mo1 += r1;
                    so0 += mo0; so1 += mo1;
                }
            }

            if (tid == 0) {
                out[(i * BATCH + b) * OUT_DIM + 0] = so0 / 7.0f;
                out[(i * BATCH + b) * OUT_DIM + 1] = so1 / 7.0f;
            }
        }
    }
}

extern "C" void kernel_launch(void* const* d_in, const int* in_sizes, int n_in,
                              void* d_out, int out_size, void* d_ws, size_t ws_size,
                              hipStream_t stream) {
    const float* x     = (const float*)d_in[0];
    const float* W0    = (const float*)d_in[1];
    const float* W1    = (const float*)d_in[2];
    const float* W2    = (const float*)d_in[3];
    const float* Wout  = (const float*)d_in[4];
    const float* betas = (const float*)d_in[5];
    const float* thrs  = (const float*)d_in[6];
    float* out = (float*)d_out;

    float* ws  = (float*)d_ws;
    float* W0T = ws + W0T_OFF;
    float* W1T = ws + W1T_OFF;
    float* W2T = ws + W2T_OFF;
    int* ctr = (int*)((char*)d_ws + CTR_BYTE_OFF);
    unsigned long long* zbuf = (unsigned long long*)((char*)d_ws + ZBUF_BYTE_OFF);

    {
        int n = HIDDEN * IN_DIM;
        transpose_kernel<<<(n + 255) / 256, 256, 0, stream>>>(W0, W0T, HIDDEN, IN_DIM);
    }
    {
        int n = HIDDEN * HIDDEN;
        transpose_kernel<<<(n + 255) / 256, 256, 0, stream>>>(W1, W1T, HIDDEN, HIDDEN);
        transpose_kernel<<<(n + 255) / 256, 256, 0, stream>>>(W2, W2T, HIDDEN, HIDDEN);
    }

    // zero the pad row (index 512) of W1T/W2T, and the progress counters
    hipMemsetAsync(W1T + (size_t)HIDDEN * HIDDEN, 0, HIDDEN * sizeof(float), stream);
    hipMemsetAsync(W2T + (size_t)HIDDEN * HIDDEN, 0, HIDDEN * sizeof(float), stream);
    hipMemsetAsync((char*)d_ws + CTR_BYTE_OFF, 0, 1024, stream);

    snn_pipe_kernel<<<2 * BATCH, HIDDEN, 0, stream>>>(
        x, Wout, betas, thrs, W0T, W1T, W2T, zbuf, ctr, out);
}